// Round 2
// baseline (203.268 us; speedup 1.0000x reference)
//
#include <hip/hip_runtime.h>

// HMaxPool2D on (32,128,128,64) f32, NHWC.
// Closed form of _build(128,128): oh=ow=43, pooling center (unpadded x coords)
// = (3*oi, 3*oj + (oi&1)).  Window rows rx-1..rx+1; middle row uses cols
// cx-1..cx+1; top/bottom rows use cols {cx-par, cx-par+1} (par = oi&1).
// max(g*mask) == max(0, max over the 7 active entries); OOB reads -> 0,
// absorbed by the clamp.
//
// Bounds analysis (H=W=128, oi,oj in [0,42]):
//   rx+1 = 3*oi+1 <= 127   always valid
//   rx-1 invalid only when oi==0
//   ca = cx-par in [0,126], cb = ca+1 <= 127   always valid
//   cx-1 invalid only when cx==0; cx+1 invalid only when cx==127
//
// Round-2 experiment: launch twice (idempotent) so dur_us_new - dur_us_old
// estimates one kernel dispatch's true duration (harness fills dominate dur_us).

constexpr int B = 32, H = 128, W = 128, C = 64;
constexpr int OH = 43, OW = 43;
constexpr int C4 = C / 4;             // 16 float4 per pixel
constexpr int NV = B * OH * OW * C4;  // 946688 = 3698 * 256 exactly

__global__ __launch_bounds__(256)
void hmaxpool_kernel(const float4* __restrict__ x, float4* __restrict__ out) {
    int g = blockIdx.x * 256 + threadIdx.x;

    int c4 = g & (C4 - 1);   // channel quad
    int p  = g >> 4;         // pixel index
    int oj = p % OW;
    int t  = p / OW;
    int oi = t % OH;
    int b  = t / OH;

    int par = oi & 1;
    int rx  = 3 * oi;         // center row in x coords
    int cx  = 3 * oj + par;   // center col in x coords

    const float4* px = x + (size_t)(b * H + rx) * W * C4 + c4;  // row rx, col 0
    const int RS = W * C4;    // row stride in float4

    float4 m = make_float4(0.f, 0.f, 0.f, 0.f);
    auto acc = [&](const float4* base, int c) {
        float4 v = base[c * C4];
        m.x = fmaxf(m.x, v.x);
        m.y = fmaxf(m.y, v.y);
        m.z = fmaxf(m.z, v.z);
        m.w = fmaxf(m.w, v.w);
    };

    // middle row (rx): cols cx-1, cx, cx+1 (edge-guarded)
    if (cx > 0)   acc(px, cx - 1);
    acc(px, cx);
    if (cx < 127) acc(px, cx + 1);

    // bottom row (rx+1): always valid
    int ca = cx - par;
    acc(px + RS, ca);
    acc(px + RS, ca + 1);

    // top row (rx-1): valid unless oi==0
    if (oi > 0) {
        acc(px - RS, ca);
        acc(px - RS, ca + 1);
    }

    out[g] = m;
}

extern "C" void kernel_launch(void* const* d_in, const int* in_sizes, int n_in,
                              void* d_out, int out_size, void* d_ws, size_t ws_size,
                              hipStream_t stream) {
    const float4* x = (const float4*)d_in[0];
    float4* out = (float4*)d_out;
    // Launch twice: idempotent. The dur_us delta vs round 1 measures one
    // kernel dispatch's duration through the harness timer.
    hipLaunchKernelGGL(hmaxpool_kernel, dim3(NV / 256), dim3(256), 0, stream, x, out);
    hipLaunchKernelGGL(hmaxpool_kernel, dim3(NV / 256), dim3(256), 0, stream, x, out);
}

// Round 3
// 185.291 us; speedup vs baseline: 1.0970x; 1.0970x over previous
//
#include <hip/hip_runtime.h>

// HMaxPool2D on (32,128,128,64) f32, NHWC.
// Closed form of _build(128,128): oh=ow=43, pooling center (unpadded x coords)
// = (3*oi, 3*oj + (oi&1)).  Window rows rx-1..rx+1; middle row uses cols
// cx-1..cx+1; top/bottom rows use cols {cx-par, cx-par+1} (par = oi&1).
// max(g*mask) == max(0, max over the 7 active entries); OOB reads -> 0,
// absorbed by the clamp.
//
// Bounds analysis (H=W=128, oi,oj in [0,42]):
//   rx+1 = 3*oi+1 <= 127   always valid
//   rx-1 invalid only when oi==0
//   ca = cx-par in [0,126], cb = ca+1 <= 127   always valid
//   cx-1 invalid only when cx==0; cx+1 invalid only when cx==127
//
// Traffic analysis: the 7-point windows tile the input with ZERO overlap
// (disjoint col-triples on center rows, disjoint pairs on off rows; each
// off-row is used by exactly one window row). Unique traffic = ~105 MB read
// + 15 MB write ~= 19 us at 6.3 TB/s. Measured single-dispatch time (R2
// double-launch delta): ~16.8 us -> at the memory roofline (L3 assists).
// Harness dur_us (~186 us) is dominated by its own 536 MB poison fills.

constexpr int B = 32, H = 128, W = 128, C = 64;
constexpr int OH = 43, OW = 43;
constexpr int C4 = C / 4;             // 16 float4 per pixel
constexpr int NV = B * OH * OW * C4;  // 946688 = 3698 * 256 exactly

__global__ __launch_bounds__(256)
void hmaxpool_kernel(const float4* __restrict__ x, float4* __restrict__ out) {
    int g = blockIdx.x * 256 + threadIdx.x;

    int c4 = g & (C4 - 1);   // channel quad
    int p  = g >> 4;         // pixel index
    int oj = p % OW;
    int t  = p / OW;
    int oi = t % OH;
    int b  = t / OH;

    int par = oi & 1;
    int rx  = 3 * oi;         // center row in x coords
    int cx  = 3 * oj + par;   // center col in x coords

    const float4* px = x + (size_t)(b * H + rx) * W * C4 + c4;  // row rx, col 0
    const int RS = W * C4;    // row stride in float4

    float4 m = make_float4(0.f, 0.f, 0.f, 0.f);
    auto acc = [&](const float4* base, int c) {
        float4 v = base[c * C4];
        m.x = fmaxf(m.x, v.x);
        m.y = fmaxf(m.y, v.y);
        m.z = fmaxf(m.z, v.z);
        m.w = fmaxf(m.w, v.w);
    };

    // middle row (rx): cols cx-1, cx, cx+1 (edge-guarded)
    if (cx > 0)   acc(px, cx - 1);
    acc(px, cx);
    if (cx < 127) acc(px, cx + 1);

    // bottom row (rx+1): always valid
    int ca = cx - par;
    acc(px + RS, ca);
    acc(px + RS, ca + 1);

    // top row (rx-1): valid unless oi==0
    if (oi > 0) {
        acc(px - RS, ca);
        acc(px - RS, ca + 1);
    }

    out[g] = m;
}

extern "C" void kernel_launch(void* const* d_in, const int* in_sizes, int n_in,
                              void* d_out, int out_size, void* d_ws, size_t ws_size,
                              hipStream_t stream) {
    const float4* x = (const float4*)d_in[0];
    float4* out = (float4*)d_out;
    hipLaunchKernelGGL(hmaxpool_kernel, dim3(NV / 256), dim3(256), 0, stream, x, out);
}